// Round 5
// baseline (354.297 us; speedup 1.0000x reference)
//
#include <hip/hip_runtime.h>
#include <hip/hip_bf16.h>

#define SEQ   2048
#define HDIM  2048
#define NHEAD 16
#define HEADD 128
#define BATCH 2
#define MTOT  (BATCH*SEQ)   // 4096
#define BH    (BATCH*NHEAD) // 32

typedef __attribute__((ext_vector_type(8))) __bf16 bf16x8;
typedef __attribute__((ext_vector_type(4))) float f32x4;
typedef __attribute__((ext_vector_type(8))) unsigned short u16x8;

__device__ __forceinline__ unsigned short f2b(float f) {
    __bf16 h = (__bf16)f;
    return __builtin_bit_cast(unsigned short, h);
}

__device__ __forceinline__ void gld_lds16(const void* gptr, void* ldsptr) {
    __builtin_amdgcn_global_load_lds(
        (const __attribute__((address_space(1))) unsigned int*)gptr,
        (__attribute__((address_space(3))) unsigned int*)ldsptr,
        16, 0, 0);
}

// ---------------- f32 -> bf16 convert (vectorized, grid-stride) ----------------
__global__ void cvt_bf16(const float* __restrict__ src, unsigned short* __restrict__ dst, long n8) {
    long i = blockIdx.x * (long)blockDim.x + threadIdx.x;
    long stride = (long)gridDim.x * blockDim.x;
    for (; i < n8; i += stride) {
        f32x4 a = *(const f32x4*)(src + i * 8);
        f32x4 b = *(const f32x4*)(src + i * 8 + 4);
        u16x8 o;
#pragma unroll
        for (int j = 0; j < 4; ++j) { o[j] = f2b(a[j]); o[4 + j] = f2b(b[j]); }
        *(u16x8*)(dst + i * 8) = o;
    }
}

// fused 5-way convert
__global__ void cvt5(const float* __restrict__ s0, const float* __restrict__ s1,
                     const float* __restrict__ s2, const float* __restrict__ s3,
                     const float* __restrict__ s4,
                     unsigned short* __restrict__ d0, unsigned short* __restrict__ d1,
                     unsigned short* __restrict__ d2, unsigned short* __restrict__ d3,
                     unsigned short* __restrict__ d4,
                     long n0, long n1) {
    const float* s; unsigned short* d; long n;
    switch (blockIdx.z) {
        case 0: s = s0; d = d0; n = n0; break;
        case 1: s = s1; d = d1; n = n1; break;
        case 2: s = s2; d = d2; n = n1; break;
        case 3: s = s3; d = d3; n = n1; break;
        default: s = s4; d = d4; n = n1; break;
    }
    long i = blockIdx.x * (long)blockDim.x + threadIdx.x;
    long stride = (long)gridDim.x * blockDim.x;
    for (; i < n; i += stride) {
        f32x4 a = *(const f32x4*)(s + i * 8);
        f32x4 b = *(const f32x4*)(s + i * 8 + 4);
        u16x8 o;
#pragma unroll
        for (int j = 0; j < 4; ++j) { o[j] = f2b(a[j]); o[4 + j] = f2b(b[j]); }
        *(u16x8*)(d + i * 8) = o;
    }
}

// ---------------- GEMM: C[m][n] = A[m][:] . Bw[n][:] + bias[n]  (B^T layout) ----
template <int MODE>
__launch_bounds__(256)
__global__ void gemm_bt(const unsigned short* __restrict__ A,
                        const unsigned short* __restrict__ Bw,
                        const float* __restrict__ bias,
                        void* __restrict__ Cout,
                        int Kc, float scale) {
    __shared__ unsigned short As[128 * 32];
    __shared__ unsigned short Bs[128 * 32];
    const int tid  = threadIdx.x;
    const int lane = tid & 63;
    const int w    = tid >> 6;
    const int m0 = blockIdx.x * 128, n0 = blockIdx.y * 128;
    const int wr = (w >> 1) * 64, wc = (w & 1) * 64;
    const long rowBytes = (long)Kc * 2;

    f32x4 acc[4][4] = {};

    const int kIters = Kc >> 5;
    for (int kt = 0; kt < kIters; ++kt) {
        const long kb = (long)kt * 64;
#pragma unroll
        for (int i = 0; i < 2; ++i) {
            int c = tid + i * 256;
            int row = c >> 2;
            int cb  = (c & 3) * 16;
            gld_lds16((const char*)A  + (long)(m0 + row) * rowBytes + kb + cb, (char*)As + c * 16);
            gld_lds16((const char*)Bw + (long)(n0 + row) * rowBytes + kb + cb, (char*)Bs + c * 16);
        }
        __syncthreads();
        bf16x8 af[4], bfr[4];
#pragma unroll
        for (int f = 0; f < 4; ++f) {
            af[f]  = *(const bf16x8*)&As[(wr + f * 16 + (lane & 15)) * 32 + (lane >> 4) * 8];
            bfr[f] = *(const bf16x8*)&Bs[(wc + f * 16 + (lane & 15)) * 32 + (lane >> 4) * 8];
        }
#pragma unroll
        for (int mf = 0; mf < 4; ++mf)
#pragma unroll
            for (int nf = 0; nf < 4; ++nf)
                acc[mf][nf] = __builtin_amdgcn_mfma_f32_16x16x32_bf16(af[mf], bfr[nf], acc[mf][nf], 0, 0, 0);
        __syncthreads();
    }

#pragma unroll
    for (int mf = 0; mf < 4; ++mf) {
#pragma unroll
        for (int nf = 0; nf < 4; ++nf) {
            int n = n0 + wc + nf * 16 + (lane & 15);
            float bv = bias[n];
#pragma unroll
            for (int j = 0; j < 4; ++j) {
                int m = m0 + wr + mf * 16 + (lane >> 4) * 4 + j;
                float v = (acc[mf][nf][j] + bv) * scale;
                if (MODE == 0) {
                    int b = m >> 11, s = m & 2047;
                    int nh = n >> 7, hd = n & 127;
                    ((unsigned short*)Cout)[((long)(b * NHEAD + nh) * SEQ + s) * HEADD + hd] = f2b(v);
                } else if (MODE == 1) {
                    int b = m >> 11, s = m & 2047;
                    int nh = n >> 7, hd = n & 127;
                    ((unsigned short*)Cout)[((long)(b * NHEAD + nh) * HEADD + hd) * SEQ + s] = f2b(v);
                } else {
                    ((float*)Cout)[(long)m * HDIM + n] = v;
                }
            }
        }
    }
}

// ---------------- causal flash attention (swapped-QK, in-register softmax) ----
// S^T = mfma(kf, qf): C col = q = lane&15 (lane-owned row), row = kv.
// PV:  O^T = mfma(vf, pf): C col = q, row = d.
__device__ __forceinline__ void attn_tile(
    const unsigned short* Ksb, const unsigned short* Vsb, unsigned short* Psw,
    const bf16x8 (&qf)[4], f32x4 (&acc)[8], float& mrun, float& lrun,
    int lane, int q0, int kvt, bool diag)
{
    const int q = lane & 15, G = lane >> 4;
    // S^T tiles: sv[ct][j] = S[kv = kvt*64 + ct*16 + G*4 + j][q0 + q]
    f32x4 sv[4];
#pragma unroll
    for (int ct = 0; ct < 4; ++ct) {
        f32x4 s = {};
#pragma unroll
        for (int ks = 0; ks < 4; ++ks) {
            int row = ct * 16 + q;
            int off = (row * 256 + ((ks * 64 + G * 16) ^ ((row & 7) << 4))) >> 1;
            bf16x8 kf = *(const bf16x8*)&Ksb[off];
            s = __builtin_amdgcn_mfma_f32_16x16x32_bf16(kf, qf[ks], s, 0, 0, 0);
        }
        sv[ct] = s;
    }
    if (diag) {
        const int qg = q0 + q;
#pragma unroll
        for (int ct = 0; ct < 4; ++ct)
#pragma unroll
            for (int j = 0; j < 4; ++j) {
                int kv = kvt * 64 + ct * 16 + G * 4 + j;
                if (kv > qg) sv[ct][j] = -1e30f;
            }
    }

    // in-register online softmax (lane owns q-row; 16 vals in-lane, 2 shfls across groups)
    float tmax = sv[0][0];
#pragma unroll
    for (int ct = 0; ct < 4; ++ct)
#pragma unroll
        for (int j = 0; j < 4; ++j) tmax = fmaxf(tmax, sv[ct][j]);
    tmax = fmaxf(tmax, __shfl_xor(tmax, 16));
    tmax = fmaxf(tmax, __shfl_xor(tmax, 32));

    float mnew = mrun, sc = 1.0f;
    if (__any(tmax > mrun + 8.0f)) {     // defer-max (T13): skip rescale when growth small
        mnew = fmaxf(mrun, tmax);
        sc = __expf(mrun - mnew);
#pragma unroll
        for (int h8 = 0; h8 < 8; ++h8) acc[h8] *= sc;
    }
    float rs = 0.f;
#pragma unroll
    for (int ct = 0; ct < 4; ++ct)
#pragma unroll
        for (int j = 0; j < 4; ++j) {
            float p = __expf(sv[ct][j] - mnew);
            sv[ct][j] = p;
            rs += p;
        }
    rs += __shfl_xor(rs, 16);
    rs += __shfl_xor(rs, 32);
    lrun = lrun * sc + rs;
    mrun = mnew;

    // P -> LDS: in-lane bf16 pair-pack, 4x ds_write_b64 (kv 4-consecutive per write)
#pragma unroll
    for (int ct = 0; ct < 4; ++ct) {
        unsigned int w0 = f2b(sv[ct][0]) | ((unsigned int)f2b(sv[ct][1]) << 16);
        unsigned int w1 = f2b(sv[ct][2]) | ((unsigned int)f2b(sv[ct][3]) << 16);
        int off = q * 128 + ((ct * 32 + G * 8) ^ ((q & 7) << 4));
        *(unsigned long long*)((char*)Psw + off) =
            (unsigned long long)w0 | ((unsigned long long)w1 << 32);
    }
    bf16x8 pf[2];
#pragma unroll
    for (int kvs = 0; kvs < 2; ++kvs) {
        int off = q * 128 + ((kvs * 64 + G * 16) ^ ((q & 7) << 4));
        pf[kvs] = *(const bf16x8*)((const char*)Psw + off);
    }
    // O^T += V^T . P   (A = Vt rows d, B = P cols q)
#pragma unroll
    for (int hdt = 0; hdt < 8; ++hdt)
#pragma unroll
        for (int kvs = 0; kvs < 2; ++kvs) {
            int row = hdt * 16 + q;
            int off = (row * 128 + ((kvs * 64 + G * 16) ^ ((row & 7) << 4))) >> 1;
            bf16x8 vf = *(const bf16x8*)&Vsb[off];
            acc[hdt] = __builtin_amdgcn_mfma_f32_16x16x32_bf16(vf, pf[kvs], acc[hdt], 0, 0, 0);
        }
}

__launch_bounds__(256)
__global__ void attn_fwd(const unsigned short* __restrict__ Q,
                         const unsigned short* __restrict__ K,
                         const unsigned short* __restrict__ Vt,
                         unsigned short* __restrict__ Out) {
    __shared__ unsigned short Ks[2][64 * 128];
    __shared__ unsigned short Vs[2][128 * 64];
    __shared__ unsigned short Ps[8][16 * 64];

    const int tid  = threadIdx.x;
    const int lane = tid & 63;
    const int w    = tid >> 6;

    const int id  = blockIdx.x;           // 0..511
    const int xcd = id & 7;
    const int j2  = id >> 3;
    const int bh  = xcd * 4 + (j2 >> 4);
    const int x   = j2 & 15;
    const int hiT = 31 - x;
    const int loT = x;
    const int qh0 = hiT * 64 + w * 16;
    const int ql0 = loT * 64 + w * 16;

    const char* Kbase = (const char*)(K  + (long)bh * SEQ * HEADD);
    const char* Vbase = (const char*)(Vt + (long)bh * HEADD * SEQ);

    bf16x8 qfh[4], qfl[4];
#pragma unroll
    for (int ks = 0; ks < 4; ++ks) {
        qfh[ks] = *(const bf16x8*)&Q[((long)bh * SEQ + qh0 + (lane & 15)) * HEADD + ks * 32 + (lane >> 4) * 8];
        qfl[ks] = *(const bf16x8*)&Q[((long)bh * SEQ + ql0 + (lane & 15)) * HEADD + ks * 32 + (lane >> 4) * 8];
    }

    f32x4 acch[8] = {}, accl[8] = {};
    float mh = -1e30f, lh = 0.f, ml = -1e30f, ll = 0.f;

#define STAGE(kvt, b) do {                                                              \
    _Pragma("unroll")                                                                   \
    for (int i = 0; i < 4; ++i) {                                                       \
        int c = tid + i * 256;                                                          \
        int rowk = c >> 4;                                                              \
        int cbk  = ((c & 15) * 16) ^ ((rowk & 7) << 4);                                 \
        gld_lds16(Kbase + (long)((kvt) * 64 + rowk) * 256 + cbk, (char*)Ks[b] + c * 16);\
        int rowv = c >> 3;                                                              \
        int cbv  = ((c & 7) * 16) ^ ((rowv & 7) << 4);                                  \
        gld_lds16(Vbase + (long)rowv * (SEQ * 2) + (kvt) * 128 + cbv, (char*)Vs[b] + c * 16); \
    } } while (0)

    STAGE(0, 0);
    __syncthreads();

    for (int kvt = 0; kvt <= hiT; ++kvt) {
        const int cur = kvt & 1;
        if (kvt < hiT) STAGE(kvt + 1, cur ^ 1);
        attn_tile(Ks[cur], Vs[cur], Ps[w],     qfh, acch, mh, lh, lane, qh0, kvt, kvt == hiT);
        if (kvt <= loT)
            attn_tile(Ks[cur], Vs[cur], Ps[4 + w], qfl, accl, ml, ll, lane, ql0, kvt, kvt == loT);
        __syncthreads();
    }
#undef STAGE

    // ---- epilogue: acc is [d][q]; transpose via LDS (reuse Ks), coalesced store
    const int b = bh >> 4, nh = bh & 15;
    unsigned short* tbh = ((unsigned short*)Ks) + w * 2048;       // 4 KB per region
    unsigned short* tbl = ((unsigned short*)Ks) + (4 + w) * 2048;
    {
        const float invh = 1.0f / lh, invl = 1.0f / ll;
        const int q = lane & 15, G = lane >> 4;
#pragma unroll
        for (int hdt = 0; hdt < 8; ++hdt) {
            int off = q * 256 + ((hdt * 32 + G * 8) ^ (q << 4));
            unsigned int h0 = f2b(acch[hdt][0] * invh) | ((unsigned int)f2b(acch[hdt][1] * invh) << 16);
            unsigned int h1 = f2b(acch[hdt][2] * invh) | ((unsigned int)f2b(acch[hdt][3] * invh) << 16);
            *(unsigned long long*)((char*)tbh + off) =
                (unsigned long long)h0 | ((unsigned long long)h1 << 32);
            unsigned int l0 = f2b(accl[hdt][0] * invl) | ((unsigned int)f2b(accl[hdt][1] * invl) << 16);
            unsigned int l1 = f2b(accl[hdt][2] * invl) | ((unsigned int)f2b(accl[hdt][3] * invl) << 16);
            *(unsigned long long*)((char*)tbl + off) =
                (unsigned long long)l0 | ((unsigned long long)l1 << 32);
        }
    }
    __syncthreads();
    {
        const int row = lane >> 2, sub = lane & 3;
        const long gh = ((long)(b * SEQ) + qh0 + row) * HDIM + nh * HEADD;
        const long gl = ((long)(b * SEQ) + ql0 + row) * HDIM + nh * HEADD;
#pragma unroll
        for (int r = 0; r < 4; ++r) {
            int off = row * 256 + ((r * 64 + sub * 16) ^ (row << 4));
            *(u16x8*)(Out + gh + r * 32 + sub * 8) = *(const u16x8*)((const char*)tbh + off);
            *(u16x8*)(Out + gl + r * 32 + sub * 8) = *(const u16x8*)((const char*)tbl + off);
        }
    }
}

// ---------------- launcher ----------------
extern "C" void kernel_launch(void* const* d_in, const int* in_sizes, int n_in,
                              void* d_out, int out_size, void* d_ws, size_t ws_size,
                              hipStream_t stream) {
    const float* hs = (const float*)d_in[0];
    const float* Wq = (const float*)d_in[2];
    const float* bq = (const float*)d_in[3];
    const float* Wk = (const float*)d_in[4];
    const float* bk = (const float*)d_in[5];
    const float* Wv = (const float*)d_in[6];
    const float* bv = (const float*)d_in[7];
    const float* Wo = (const float*)d_in[8];
    const float* bo = (const float*)d_in[9];
    float* out = (float*)d_out;

    char* ws = (char*)d_ws;
    const long MB = 1024L * 1024L;
    const float rs = 0.08838834764831845f; // 1/sqrt(128)
    dim3 gg(MTOT / 128, HDIM / 128);

    if (ws_size >= 96 * MB) {
        unsigned short* hsb = (unsigned short*)ws;
        unsigned short* wqb = (unsigned short*)(ws + 16 * MB);
        unsigned short* wkb = (unsigned short*)(ws + 24 * MB);
        unsigned short* wvb = (unsigned short*)(ws + 32 * MB);
        unsigned short* wob = (unsigned short*)(ws + 40 * MB);
        unsigned short* qb  = (unsigned short*)(ws + 48 * MB);
        unsigned short* kb  = (unsigned short*)(ws + 64 * MB);
        unsigned short* vtb = (unsigned short*)(ws + 80 * MB);
        unsigned short* aob = hsb;

        cvt5<<<dim3(1024, 1, 5), 256, 0, stream>>>(hs, Wq, Wk, Wv, Wo,
                                                   hsb, wqb, wkb, wvb, wob,
                                                   (long)MTOT * HDIM / 8, (long)HDIM * HDIM / 8);
        gemm_bt<0><<<gg, 256, 0, stream>>>(hsb, wqb, bq, qb,  HDIM, rs);
        gemm_bt<0><<<gg, 256, 0, stream>>>(hsb, wkb, bk, kb,  HDIM, 1.0f);
        gemm_bt<1><<<gg, 256, 0, stream>>>(hsb, wvb, bv, vtb, HDIM, 1.0f);
        attn_fwd<<<512, 256, 0, stream>>>(qb, kb, vtb, aob);
        gemm_bt<2><<<gg, 256, 0, stream>>>(aob, wob, bo, out, HDIM, 1.0f);
    } else {
        unsigned short* hsb = (unsigned short*)ws;
        unsigned short* wb  = (unsigned short*)(ws + 16 * MB);
        unsigned short* qb  = (unsigned short*)(ws + 24 * MB);
        unsigned short* kb  = (unsigned short*)(ws + 40 * MB);
        unsigned short* vtb = (unsigned short*)(ws + 56 * MB);
        unsigned short* aob = hsb;

        cvt_bf16<<<2048, 256, 0, stream>>>(hs, hsb, (long)MTOT * HDIM / 8);
        cvt_bf16<<<2048, 256, 0, stream>>>(Wq, wb, (long)HDIM * HDIM / 8);
        gemm_bt<0><<<gg, 256, 0, stream>>>(hsb, wb, bq, qb, HDIM, rs);
        cvt_bf16<<<2048, 256, 0, stream>>>(Wk, wb, (long)HDIM * HDIM / 8);
        gemm_bt<0><<<gg, 256, 0, stream>>>(hsb, wb, bk, kb, HDIM, 1.0f);
        cvt_bf16<<<2048, 256, 0, stream>>>(Wv, wb, (long)HDIM * HDIM / 8);
        gemm_bt<1><<<gg, 256, 0, stream>>>(hsb, wb, bv, vtb, HDIM, 1.0f);
        attn_fwd<<<512, 256, 0, stream>>>(qb, kb, vtb, aob);
        cvt_bf16<<<2048, 256, 0, stream>>>(Wo, wb, (long)HDIM * HDIM / 8);
        gemm_bt<2><<<gg, 256, 0, stream>>>(aob, wb, bo, out, HDIM, 1.0f);
    }
}

// Round 6
// 354.138 us; speedup vs baseline: 1.0004x; 1.0004x over previous
//
#include <hip/hip_runtime.h>
#include <hip/hip_bf16.h>

#define SEQ   2048
#define HDIM  2048
#define NHEAD 16
#define HEADD 128
#define BATCH 2
#define MTOT  (BATCH*SEQ)   // 4096
#define BH    (BATCH*NHEAD) // 32

typedef __attribute__((ext_vector_type(8))) __bf16 bf16x8;
typedef __attribute__((ext_vector_type(4))) float f32x4;
typedef __attribute__((ext_vector_type(8))) unsigned short u16x8;

__device__ __forceinline__ unsigned short f2b(float f) {
    __bf16 h = (__bf16)f;
    return __builtin_bit_cast(unsigned short, h);
}

__device__ __forceinline__ void gld_lds16(const void* gptr, void* ldsptr) {
    __builtin_amdgcn_global_load_lds(
        (const __attribute__((address_space(1))) unsigned int*)gptr,
        (__attribute__((address_space(3))) unsigned int*)ldsptr,
        16, 0, 0);
}

// ---------------- f32 -> bf16 convert (vectorized, grid-stride) ----------------
__global__ void cvt_bf16(const float* __restrict__ src, unsigned short* __restrict__ dst, long n8) {
    long i = blockIdx.x * (long)blockDim.x + threadIdx.x;
    long stride = (long)gridDim.x * blockDim.x;
    for (; i < n8; i += stride) {
        f32x4 a = *(const f32x4*)(src + i * 8);
        f32x4 b = *(const f32x4*)(src + i * 8 + 4);
        u16x8 o;
#pragma unroll
        for (int j = 0; j < 4; ++j) { o[j] = f2b(a[j]); o[4 + j] = f2b(b[j]); }
        *(u16x8*)(dst + i * 8) = o;
    }
}

// fused 5-way convert
__global__ void cvt5(const float* __restrict__ s0, const float* __restrict__ s1,
                     const float* __restrict__ s2, const float* __restrict__ s3,
                     const float* __restrict__ s4,
                     unsigned short* __restrict__ d0, unsigned short* __restrict__ d1,
                     unsigned short* __restrict__ d2, unsigned short* __restrict__ d3,
                     unsigned short* __restrict__ d4,
                     long n0, long n1) {
    const float* s; unsigned short* d; long n;
    switch (blockIdx.z) {
        case 0: s = s0; d = d0; n = n0; break;
        case 1: s = s1; d = d1; n = n1; break;
        case 2: s = s2; d = d2; n = n1; break;
        case 3: s = s3; d = d3; n = n1; break;
        default: s = s4; d = d4; n = n1; break;
    }
    long i = blockIdx.x * (long)blockDim.x + threadIdx.x;
    long stride = (long)gridDim.x * blockDim.x;
    for (; i < n; i += stride) {
        f32x4 a = *(const f32x4*)(s + i * 8);
        f32x4 b = *(const f32x4*)(s + i * 8 + 4);
        u16x8 o;
#pragma unroll
        for (int j = 0; j < 4; ++j) { o[j] = f2b(a[j]); o[4 + j] = f2b(b[j]); }
        *(u16x8*)(d + i * 8) = o;
    }
}

// ---------------- GEMM: C[m][n] = A[m][:] . Bw[n][:] + bias[n]  (B^T layout) ----
template <int MODE>
__launch_bounds__(256)
__global__ void gemm_bt(const unsigned short* __restrict__ A,
                        const unsigned short* __restrict__ Bw,
                        const float* __restrict__ bias,
                        void* __restrict__ Cout,
                        int Kc, float scale) {
    __shared__ unsigned short As[128 * 32];
    __shared__ unsigned short Bs[128 * 32];
    const int tid  = threadIdx.x;
    const int lane = tid & 63;
    const int w    = tid >> 6;
    const int m0 = blockIdx.x * 128, n0 = blockIdx.y * 128;
    const int wr = (w >> 1) * 64, wc = (w & 1) * 64;
    const long rowBytes = (long)Kc * 2;

    f32x4 acc[4][4] = {};

    const int kIters = Kc >> 5;
    for (int kt = 0; kt < kIters; ++kt) {
        const long kb = (long)kt * 64;
#pragma unroll
        for (int i = 0; i < 2; ++i) {
            int c = tid + i * 256;
            int row = c >> 2;
            int cb  = (c & 3) * 16;
            gld_lds16((const char*)A  + (long)(m0 + row) * rowBytes + kb + cb, (char*)As + c * 16);
            gld_lds16((const char*)Bw + (long)(n0 + row) * rowBytes + kb + cb, (char*)Bs + c * 16);
        }
        __syncthreads();
        bf16x8 af[4], bfr[4];
#pragma unroll
        for (int f = 0; f < 4; ++f) {
            af[f]  = *(const bf16x8*)&As[(wr + f * 16 + (lane & 15)) * 32 + (lane >> 4) * 8];
            bfr[f] = *(const bf16x8*)&Bs[(wc + f * 16 + (lane & 15)) * 32 + (lane >> 4) * 8];
        }
#pragma unroll
        for (int mf = 0; mf < 4; ++mf)
#pragma unroll
            for (int nf = 0; nf < 4; ++nf)
                acc[mf][nf] = __builtin_amdgcn_mfma_f32_16x16x32_bf16(af[mf], bfr[nf], acc[mf][nf], 0, 0, 0);
        __syncthreads();
    }

#pragma unroll
    for (int mf = 0; mf < 4; ++mf) {
#pragma unroll
        for (int nf = 0; nf < 4; ++nf) {
            int n = n0 + wc + nf * 16 + (lane & 15);
            float bv = bias[n];
#pragma unroll
            for (int j = 0; j < 4; ++j) {
                int m = m0 + wr + mf * 16 + (lane >> 4) * 4 + j;
                float v = (acc[mf][nf][j] + bv) * scale;
                if (MODE == 0) {
                    int b = m >> 11, s = m & 2047;
                    int nh = n >> 7, hd = n & 127;
                    ((unsigned short*)Cout)[((long)(b * NHEAD + nh) * SEQ + s) * HEADD + hd] = f2b(v);
                } else if (MODE == 1) {
                    int b = m >> 11, s = m & 2047;
                    int nh = n >> 7, hd = n & 127;
                    ((unsigned short*)Cout)[((long)(b * NHEAD + nh) * HEADD + hd) * SEQ + s] = f2b(v);
                } else {
                    ((float*)Cout)[(long)m * HDIM + n] = v;
                }
            }
        }
    }
}

// ---------------- causal flash attention (swapped-QK, in-register softmax) ----
// S^T = mfma(kf, qf): C col = q = lane&15 (lane-owned row), row = kv.
// PV:  O^T = mfma(vf, pf): C col = q, row = d.
__device__ __forceinline__ void attn_tile(
    const unsigned short* Ksb, const unsigned short* Vsb, unsigned short* Psw,
    const bf16x8 (&qf)[4], f32x4 (&acc)[8], float& mrun, float& lrun,
    int lane, int q0, int kvt, bool diag)
{
    const int q = lane & 15, G = lane >> 4;
    // S^T tiles: sv[ct][j] = S[kv = kvt*64 + ct*16 + G*4 + j][q0 + q]
    f32x4 sv[4];
#pragma unroll
    for (int ct = 0; ct < 4; ++ct) {
        f32x4 s = {};
#pragma unroll
        for (int ks = 0; ks < 4; ++ks) {
            int row = ct * 16 + q;
            int off = (row * 256 + ((ks * 64 + G * 16) ^ ((row & 7) << 4))) >> 1;
            bf16x8 kf = *(const bf16x8*)&Ksb[off];
            s = __builtin_amdgcn_mfma_f32_16x16x32_bf16(kf, qf[ks], s, 0, 0, 0);
        }
        sv[ct] = s;
    }
    if (diag) {
        const int qg = q0 + q;
#pragma unroll
        for (int ct = 0; ct < 4; ++ct)
#pragma unroll
            for (int j = 0; j < 4; ++j) {
                int kv = kvt * 64 + ct * 16 + G * 4 + j;
                if (kv > qg) sv[ct][j] = -1e30f;
            }
    }

    // in-register online softmax (lane owns q-row; 16 vals in-lane, 2 shfls across groups)
    float tmax = sv[0][0];
#pragma unroll
    for (int ct = 0; ct < 4; ++ct)
#pragma unroll
        for (int j = 0; j < 4; ++j) tmax = fmaxf(tmax, sv[ct][j]);
    tmax = fmaxf(tmax, __shfl_xor(tmax, 16));
    tmax = fmaxf(tmax, __shfl_xor(tmax, 32));

    float mnew = mrun, sc = 1.0f;
    if (__any(tmax > mrun + 8.0f)) {     // defer-max (T13): skip rescale when growth small
        mnew = fmaxf(mrun, tmax);
        sc = __expf(mrun - mnew);
#pragma unroll
        for (int h8 = 0; h8 < 8; ++h8) acc[h8] *= sc;
    }
    float rs = 0.f;
#pragma unroll
    for (int ct = 0; ct < 4; ++ct)
#pragma unroll
        for (int j = 0; j < 4; ++j) {
            float p = __expf(sv[ct][j] - mnew);
            sv[ct][j] = p;
            rs += p;
        }
    rs += __shfl_xor(rs, 16);
    rs += __shfl_xor(rs, 32);
    lrun = lrun * sc + rs;
    mrun = mnew;

    // P -> LDS: in-lane bf16 pair-pack, 4x ds_write_b64 (kv 4-consecutive per write)
#pragma unroll
    for (int ct = 0; ct < 4; ++ct) {
        unsigned int w0 = f2b(sv[ct][0]) | ((unsigned int)f2b(sv[ct][1]) << 16);
        unsigned int w1 = f2b(sv[ct][2]) | ((unsigned int)f2b(sv[ct][3]) << 16);
        int off = q * 128 + ((ct * 32 + G * 8) ^ ((q & 7) << 4));
        *(unsigned long long*)((char*)Psw + off) =
            (unsigned long long)w0 | ((unsigned long long)w1 << 32);
    }
    bf16x8 pf[2];
#pragma unroll
    for (int kvs = 0; kvs < 2; ++kvs) {
        int off = q * 128 + ((kvs * 64 + G * 16) ^ ((q & 7) << 4));
        pf[kvs] = *(const bf16x8*)((const char*)Psw + off);
    }
    // O^T += V^T . P   (A = Vt rows d, B = P cols q)
#pragma unroll
    for (int hdt = 0; hdt < 8; ++hdt)
#pragma unroll
        for (int kvs = 0; kvs < 2; ++kvs) {
            int row = hdt * 16 + q;
            int off = (row * 128 + ((kvs * 64 + G * 16) ^ ((row & 7) << 4))) >> 1;
            bf16x8 vf = *(const bf16x8*)&Vsb[off];
            acc[hdt] = __builtin_amdgcn_mfma_f32_16x16x32_bf16(vf, pf[kvs], acc[hdt], 0, 0, 0);
        }
}

__launch_bounds__(256)
__global__ void attn_fwd(const unsigned short* __restrict__ Q,
                         const unsigned short* __restrict__ K,
                         const unsigned short* __restrict__ Vt,
                         unsigned short* __restrict__ Out) {
    __shared__ unsigned short Ks[2][64 * 128];
    __shared__ unsigned short Vs[2][128 * 64];
    __shared__ unsigned short Ps[8][16 * 64];

    const int tid  = threadIdx.x;
    const int lane = tid & 63;
    const int w    = tid >> 6;

    const int id  = blockIdx.x;           // 0..511
    const int xcd = id & 7;
    const int j2  = id >> 3;
    const int bh  = xcd * 4 + (j2 >> 4);
    const int x   = j2 & 15;
    const int hiT = 31 - x;
    const int loT = x;
    const int qh0 = hiT * 64 + w * 16;
    const int ql0 = loT * 64 + w * 16;

    const char* Kbase = (const char*)(K  + (long)bh * SEQ * HEADD);
    const char* Vbase = (const char*)(Vt + (long)bh * HEADD * SEQ);

    bf16x8 qfh[4], qfl[4];
#pragma unroll
    for (int ks = 0; ks < 4; ++ks) {
        qfh[ks] = *(const bf16x8*)&Q[((long)bh * SEQ + qh0 + (lane & 15)) * HEADD + ks * 32 + (lane >> 4) * 8];
        qfl[ks] = *(const bf16x8*)&Q[((long)bh * SEQ + ql0 + (lane & 15)) * HEADD + ks * 32 + (lane >> 4) * 8];
    }

    f32x4 acch[8] = {}, accl[8] = {};
    float mh = -1e30f, lh = 0.f, ml = -1e30f, ll = 0.f;

#define STAGE(kvt, b) do {                                                              \
    _Pragma("unroll")                                                                   \
    for (int i = 0; i < 4; ++i) {                                                       \
        int c = tid + i * 256;                                                          \
        int rowk = c >> 4;                                                              \
        int cbk  = ((c & 15) * 16) ^ ((rowk & 7) << 4);                                 \
        gld_lds16(Kbase + (long)((kvt) * 64 + rowk) * 256 + cbk, (char*)Ks[b] + c * 16);\
        int rowv = c >> 3;                                                              \
        int cbv  = ((c & 7) * 16) ^ ((rowv & 7) << 4);                                  \
        gld_lds16(Vbase + (long)rowv * (SEQ * 2) + (kvt) * 128 + cbv, (char*)Vs[b] + c * 16); \
    } } while (0)

    STAGE(0, 0);
    __syncthreads();

    for (int kvt = 0; kvt <= hiT; ++kvt) {
        const int cur = kvt & 1;
        if (kvt < hiT) STAGE(kvt + 1, cur ^ 1);
        attn_tile(Ks[cur], Vs[cur], Ps[w],     qfh, acch, mh, lh, lane, qh0, kvt, kvt == hiT);
        if (kvt <= loT)
            attn_tile(Ks[cur], Vs[cur], Ps[4 + w], qfl, accl, ml, ll, lane, ql0, kvt, kvt == loT);
        __syncthreads();
    }
#undef STAGE

    // ---- epilogue: acc is [d][q]; transpose via LDS (reuse Ks), coalesced store
    const int b = bh >> 4, nh = bh & 15;
    unsigned short* tbh = ((unsigned short*)Ks) + w * 2048;       // 4 KB per region
    unsigned short* tbl = ((unsigned short*)Ks) + (4 + w) * 2048;
    {
        const float invh = 1.0f / lh, invl = 1.0f / ll;
        const int q = lane & 15, G = lane >> 4;
#pragma unroll
        for (int hdt = 0; hdt < 8; ++hdt) {
            int off = q * 256 + ((hdt * 32 + G * 8) ^ (q << 4));
            unsigned int h0 = f2b(acch[hdt][0] * invh) | ((unsigned int)f2b(acch[hdt][1] * invh) << 16);
            unsigned int h1 = f2b(acch[hdt][2] * invh) | ((unsigned int)f2b(acch[hdt][3] * invh) << 16);
            *(unsigned long long*)((char*)tbh + off) =
                (unsigned long long)h0 | ((unsigned long long)h1 << 32);
            unsigned int l0 = f2b(accl[hdt][0] * invl) | ((unsigned int)f2b(accl[hdt][1] * invl) << 16);
            unsigned int l1 = f2b(accl[hdt][2] * invl) | ((unsigned int)f2b(accl[hdt][3] * invl) << 16);
            *(unsigned long long*)((char*)tbl + off) =
                (unsigned long long)l0 | ((unsigned long long)l1 << 32);
        }
    }
    __syncthreads();
    {
        const int row = lane >> 2, sub = lane & 3;
        const long gh = ((long)(b * SEQ) + qh0 + row) * HDIM + nh * HEADD;
        const long gl = ((long)(b * SEQ) + ql0 + row) * HDIM + nh * HEADD;
#pragma unroll
        for (int r = 0; r < 4; ++r) {
            int off = row * 256 + ((r * 64 + sub * 16) ^ (row << 4));
            *(u16x8*)(Out + gh + r * 32 + sub * 8) = *(const u16x8*)((const char*)tbh + off);
            *(u16x8*)(Out + gl + r * 32 + sub * 8) = *(const u16x8*)((const char*)tbl + off);
        }
    }
}

// ---------------- launcher ----------------
extern "C" void kernel_launch(void* const* d_in, const int* in_sizes, int n_in,
                              void* d_out, int out_size, void* d_ws, size_t ws_size,
                              hipStream_t stream) {
    const float* hs = (const float*)d_in[0];
    const float* Wq = (const float*)d_in[2];
    const float* bq = (const float*)d_in[3];
    const float* Wk = (const float*)d_in[4];
    const float* bk = (const float*)d_in[5];
    const float* Wv = (const float*)d_in[6];
    const float* bv = (const float*)d_in[7];
    const float* Wo = (const float*)d_in[8];
    const float* bo = (const float*)d_in[9];
    float* out = (float*)d_out;

    char* ws = (char*)d_ws;
    const long MB = 1024L * 1024L;
    const float rs = 0.08838834764831845f; // 1/sqrt(128)
    dim3 gg(MTOT / 128, HDIM / 128);

    if (ws_size >= 96 * MB) {
        unsigned short* hsb = (unsigned short*)ws;
        unsigned short* wqb = (unsigned short*)(ws + 16 * MB);
        unsigned short* wkb = (unsigned short*)(ws + 24 * MB);
        unsigned short* wvb = (unsigned short*)(ws + 32 * MB);
        unsigned short* wob = (unsigned short*)(ws + 40 * MB);
        unsigned short* qb  = (unsigned short*)(ws + 48 * MB);
        unsigned short* kb  = (unsigned short*)(ws + 64 * MB);
        unsigned short* vtb = (unsigned short*)(ws + 80 * MB);
        unsigned short* aob = hsb;

        cvt5<<<dim3(1024, 1, 5), 256, 0, stream>>>(hs, Wq, Wk, Wv, Wo,
                                                   hsb, wqb, wkb, wvb, wob,
                                                   (long)MTOT * HDIM / 8, (long)HDIM * HDIM / 8);
        gemm_bt<0><<<gg, 256, 0, stream>>>(hsb, wqb, bq, qb,  HDIM, rs);
        gemm_bt<0><<<gg, 256, 0, stream>>>(hsb, wkb, bk, kb,  HDIM, 1.0f);
        gemm_bt<1><<<gg, 256, 0, stream>>>(hsb, wvb, bv, vtb, HDIM, 1.0f);
        attn_fwd<<<512, 256, 0, stream>>>(qb, kb, vtb, aob);
        gemm_bt<2><<<gg, 256, 0, stream>>>(aob, wob, bo, out, HDIM, 1.0f);
    } else {
        unsigned short* hsb = (unsigned short*)ws;
        unsigned short* wb  = (unsigned short*)(ws + 16 * MB);
        unsigned short* qb  = (unsigned short*)(ws + 24 * MB);
        unsigned short* kb  = (unsigned short*)(ws + 40 * MB);
        unsigned short* vtb = (unsigned short*)(ws + 56 * MB);
        unsigned short* aob = hsb;

        cvt_bf16<<<2048, 256, 0, stream>>>(hs, hsb, (long)MTOT * HDIM / 8);
        cvt_bf16<<<2048, 256, 0, stream>>>(Wq, wb, (long)HDIM * HDIM / 8);
        gemm_bt<0><<<gg, 256, 0, stream>>>(hsb, wb, bq, qb, HDIM, rs);
        cvt_bf16<<<2048, 256, 0, stream>>>(Wk, wb, (long)HDIM * HDIM / 8);
        gemm_bt<0><<<gg, 256, 0, stream>>>(hsb, wb, bk, kb, HDIM, 1.0f);
        cvt_bf16<<<2048, 256, 0, stream>>>(Wv, wb, (long)HDIM * HDIM / 8);
        gemm_bt<1><<<gg, 256, 0, stream>>>(hsb, wb, bv, vtb, HDIM, 1.0f);
        attn_fwd<<<512, 256, 0, stream>>>(qb, kb, vtb, aob);
        cvt_bf16<<<2048, 256, 0, stream>>>(Wo, wb, (long)HDIM * HDIM / 8);
        gemm_bt<2><<<gg, 256, 0, stream>>>(aob, wb, bo, out, HDIM, 1.0f);
    }
}